// Round 2
// baseline (250.635 us; speedup 1.0000x reference)
//
#include <hip/hip_runtime.h>

// MTCNN PNet stage: box generation + greedy NMS + refinement.
// Grading reference is numpy float64 -> box coords must follow f64 floors:
// floor((2bx+c)/0.3) in f64 == exact integer floor(10*(2bx+c)/3), computed
// here with integer division. With exact-integer coords, all NMS IoU
// decisions are precision-independent (margins to 0.5 are >= 4e-6 or exact).
// Batches provably cannot suppress each other (offset separation is exact),
// so global greedy NMS == 8 independent per-batch greedy NMS runs.

constexpr float kThresh = 0.6f;
constexpr float kNeg    = -1e30f;

__global__ __launch_bounds__(256)
void pnet_kernel(const float* __restrict__ probs,   // (8,32,32)
                 const float* __restrict__ reg,     // (8,4,32,32)
                 float* __restrict__ out)           // (8192,5)
{
    const int b = blockIdx.x;   // batch image
    const int t = threadIdx.x;  // 0..255, each owns 4 boxes (j*256 + t)

    __shared__ float sx1[1024], sy1[1024], sx2[1024], sy2[1024];
    __shared__ float sarea[1024], slive[1024];
    __shared__ int   skeep[1024];
    __shared__ float swv[4];
    __shared__ int   swi[4];
    __shared__ int   spick;

    // ---- init: grid boxes (exact f64-floor semantics), areas, live ----
    #pragma unroll
    for (int j = 0; j < 4; ++j) {
        const int n = j * 256 + t;           // local box index = y*32 + x
        const float score = probs[b * 1024 + n];
        const int ix = n & 31;
        const int iy = n >> 5;
        // floor((STRIDE*x + 1)/SCALE) under f64 == (20x+10)/3 exactly
        const float x1 = (float)((20 * ix + 10) / 3);
        const float y1 = (float)((20 * iy + 10) / 3);
        const float x2 = (float)((20 * ix + 120) / 3);
        const float y2 = (float)((20 * iy + 120) / 3);
        sx1[n] = x1; sy1[n] = y1; sx2[n] = x2; sy2[n] = y2;
        sarea[n] = (x2 - x1 + 1.0f) * (y2 - y1 + 1.0f);
        slive[n] = (score >= kThresh) ? score : kNeg;
        skeep[n] = 0;
    }
    __syncthreads();

    const int lane = t & 63;
    const int wid  = t >> 6;

    // ---- greedy NMS: pick per-batch argmax, suppress, repeat ----
    for (;;) {
        // per-thread argmax over its 4 boxes (ascending index: first-max
        // wins ties, matching argmax lowest-index semantics)
        float v  = slive[t];
        int   vi = t;
        #pragma unroll
        for (int j = 1; j < 4; ++j) {
            const int n = j * 256 + t;
            const float c = slive[n];
            if (c > v) { v = c; vi = n; }
        }
        // wave (64-lane) reduce with low-index tie-break
        #pragma unroll
        for (int o = 32; o >= 1; o >>= 1) {
            const float ov = __shfl_down(v, o);
            const int   oi = __shfl_down(vi, o);
            if (ov > v || (ov == v && oi < vi)) { v = ov; vi = oi; }
        }
        if (lane == 0) { swv[wid] = v; swi[wid] = vi; }
        __syncthreads();
        if (t == 0) {
            float bv = swv[0]; int bi = swi[0];
            #pragma unroll
            for (int w = 1; w < 4; ++w) {
                const float ov = swv[w]; const int oi = swi[w];
                if (ov > bv || (ov == bv && oi < bi)) { bv = ov; bi = oi; }
            }
            // once the max drops to NEG, all remaining reference scan
            // iterations are no-ops -> safe to terminate
            spick = (bv > kNeg * 0.5f) ? bi : -1;
        }
        __syncthreads();
        const int p = spick;
        if (p < 0) break;

        const float px1 = sx1[p], py1 = sy1[p], px2 = sx2[p], py2 = sy2[p];
        const float pa  = sarea[p];
        if (t == 0) skeep[p] = 1;
        #pragma unroll
        for (int j = 0; j < 4; ++j) {
            const int n = j * 256 + t;
            const float xx1 = fmaxf(px1, sx1[n]);
            const float yy1 = fmaxf(py1, sy1[n]);
            const float xx2 = fminf(px2, sx2[n]);
            const float yy2 = fminf(py2, sy2[n]);
            const float iw = fmaxf(0.0f, xx2 - xx1 + 1.0f);
            const float ih = fmaxf(0.0f, yy2 - yy1 + 1.0f);
            const float inter = iw * ih;
            // all quantities are exact small integers; iou vs 0.5 decision
            // is identical under f32 and f64
            const float iou = inter / (pa + sarea[n] - inter);
            if (iou > 0.5f) slive[n] = kNeg;   // includes p itself (iou==1)
        }
        __syncthreads();
    }

    // ---- epilogue: refine boxes, square them, gate by keep ----
    #pragma unroll
    for (int j = 0; j < 4; ++j) {
        const int n = j * 256 + t;
        const float score = probs[b * 1024 + n];
        const float x1 = sx1[n], y1 = sy1[n], x2 = sx2[n], y2 = sy2[n];
        // reg4[n, c] = reg[b, c, y, x]
        const float r0 = reg[b * 4096 + 0 * 1024 + n];
        const float r1 = reg[b * 4096 + 1 * 1024 + n];
        const float r2 = reg[b * 4096 + 2 * 1024 + n];
        const float r3 = reg[b * 4096 + 3 * 1024 + n];
        const float w = x2 - x1, h = y2 - y1;
        const float qq1 = x1 + r0 * w;
        const float qq2 = y1 + r1 * h;
        const float qq3 = x2 + r2 * w;
        const float qq4 = y2 + r3 * h;
        const float hh = qq4 - qq2, ww = qq3 - qq1;
        const float l = fmaxf(ww, hh);
        const float rx1 = qq1 + ww * 0.5f - l * 0.5f;
        const float ry1 = qq2 + hh * 0.5f - l * 0.5f;
        const float rx2 = rx1 + l;
        const float ry2 = ry1 + l;
        const float kf = (float)skeep[n];
        float* o = out + (size_t)(b * 1024 + n) * 5;
        o[0] = rx1 * kf;
        o[1] = ry1 * kf;
        o[2] = rx2 * kf;
        o[3] = ry2 * kf;
        o[4] = score * kf;
    }
}

extern "C" void kernel_launch(void* const* d_in, const int* in_sizes, int n_in,
                              void* d_out, int out_size, void* d_ws, size_t ws_size,
                              hipStream_t stream) {
    const float* probs = (const float*)d_in[0];   // 8192 f32
    const float* reg   = (const float*)d_in[1];   // 32768 f32
    float* out = (float*)d_out;                   // 40960 f32
    pnet_kernel<<<8, 256, 0, stream>>>(probs, reg, out);
}

// Round 3
// 21.562 us; speedup vs baseline: 11.6240x; 11.6240x over previous
//
#include <hip/hip_runtime.h>

// MTCNN PNet stage: box gen + greedy NMS + refinement.
// NMS is computed as a parallel monotone fixed point instead of a sequential
// scan: conflicts (IoU>0.5) are provably confined to the 3x3 grid
// neighborhood (exact-integer analysis over all mod-3 coordinate phases:
// max IoU at |dx|=2 is 950/1938 = 0.490 < 0.5). A box is KEPT iff all
// higher-priority (score desc, index asc) conflicting neighbors are DEAD,
// DEAD iff any such neighbor is KEPT — iterated to convergence this equals
// the reference's greedy scan exactly, and is race-safe (statuses are
// monotone UNKNOWN->{KEPT,DEAD} and every written mark is final+correct).
// All box coords are exact integers: floor((2v+c)/0.3) under f64 ==
// (20v+c*10)/3 integer division; IoU>0.5 <=> 3*inter > areaA+areaB (exact,
// division-free, identical decision to the f64 numpy reference).
// Batches provably cannot suppress each other -> one block per batch.

constexpr float kThresh = 0.6f;

#define ST_UNK 0
#define ST_KEEP 1
#define ST_DEAD 2

__global__ __launch_bounds__(256)
void pnet_kernel(const float* __restrict__ probs,   // (8,32,32)
                 const float* __restrict__ reg,     // (8,4,32,32)
                 float* __restrict__ out)           // (8192,5)
{
    const int b = blockIdx.x;
    const int t = threadIdx.x;

    __shared__ float         ssc[1024];      // scores
    __shared__ unsigned int  smhp[1024];     // 8-bit hp-conflict masks
    __shared__ unsigned char sst[34 * 34];   // padded status grid
    __shared__ int           schanged;

    // ---- init: statuses (border = DEAD), scores ----
    for (int i = t; i < 34 * 34; i += 256) sst[i] = ST_DEAD;
    #pragma unroll
    for (int j = 0; j < 4; ++j) {
        const int n = j * 256 + t;
        ssc[n] = probs[b * 1024 + n];
    }
    __syncthreads();
    #pragma unroll
    for (int j = 0; j < 4; ++j) {
        const int n = j * 256 + t;
        const int x = n & 31, y = n >> 5;
        sst[(y + 1) * 34 + (x + 1)] = (ssc[n] >= kThresh) ? ST_UNK : ST_DEAD;
    }
    __syncthreads();

    // ---- per-box mask of higher-priority conflicting neighbors ----
    #pragma unroll
    for (int j = 0; j < 4; ++j) {
        const int n = j * 256 + t;
        const int x = n & 31, y = n >> 5;
        const float sn = ssc[n];
        const int x1n = (20 * x + 10) / 3, x2n = (20 * x + 120) / 3;
        const int y1n = (20 * y + 10) / 3, y2n = (20 * y + 120) / 3;
        const int an = (x2n - x1n + 1) * (y2n - y1n + 1);
        unsigned int m = 0;
        int r = 0;
        #pragma unroll
        for (int dy = -1; dy <= 1; ++dy) {
            #pragma unroll
            for (int dx = -1; dx <= 1; ++dx) {
                if (dx == 0 && dy == 0) continue;
                const int xj = x + dx, yj = y + dy;
                if ((unsigned)xj < 32u && (unsigned)yj < 32u) {
                    const int jn = yj * 32 + xj;
                    const float sj = ssc[jn];
                    // invalid neighbors (score<0.6) are automatically lower
                    // priority than any valid box -> excluded here
                    const bool hp = (sj > sn) || (sj == sn && jn < n);
                    if (hp) {
                        const int x1j = (20 * xj + 10) / 3, x2j = (20 * xj + 120) / 3;
                        const int y1j = (20 * yj + 10) / 3, y2j = (20 * yj + 120) / 3;
                        const int aj = (x2j - x1j + 1) * (y2j - y1j + 1);
                        const int iw = min(x2n, x2j) - max(x1n, x1j) + 1;
                        const int ih = min(y2n, y2j) - max(y1n, y1j) + 1;
                        const int inter = max(iw, 0) * max(ih, 0);
                        if (3 * inter > an + aj) m |= (1u << r);
                    }
                }
                ++r;
            }
        }
        smhp[n] = m;
    }

    // ---- fixed-point rounds ----
    for (;;) {
        if (t == 0) schanged = 0;
        __syncthreads();
        #pragma unroll
        for (int j = 0; j < 4; ++j) {
            const int n = j * 256 + t;
            const int x = n & 31, y = n >> 5;
            const int base = (y + 1) * 34 + (x + 1);
            if (sst[base] == ST_UNK) {
                const unsigned int m = smhp[n];
                bool anyKept = false, anyUnk = false;
                int r = 0;
                #pragma unroll
                for (int dy = -1; dy <= 1; ++dy) {
                    #pragma unroll
                    for (int dx = -1; dx <= 1; ++dx) {
                        if (dx == 0 && dy == 0) continue;
                        if (m & (1u << r)) {
                            const unsigned char s = sst[base + dy * 34 + dx];
                            anyKept |= (s == ST_KEEP);
                            anyUnk  |= (s == ST_UNK);
                        }
                        ++r;
                    }
                }
                if (anyKept)      { sst[base] = ST_DEAD; schanged = 1; }
                else if (!anyUnk) { sst[base] = ST_KEEP; schanged = 1; }
            }
        }
        __syncthreads();
        const int done = (schanged == 0);
        __syncthreads();   // all reads of schanged complete before reset
        if (done) break;
    }

    // ---- epilogue: refine, square, gate by keep (verified in round 2) ----
    #pragma unroll
    for (int j = 0; j < 4; ++j) {
        const int n = j * 256 + t;
        const int x = n & 31, y = n >> 5;
        const float score = ssc[n];
        const float x1 = (float)((20 * x + 10) / 3);
        const float y1 = (float)((20 * y + 10) / 3);
        const float x2 = (float)((20 * x + 120) / 3);
        const float y2 = (float)((20 * y + 120) / 3);
        const float r0 = reg[b * 4096 + 0 * 1024 + n];
        const float r1 = reg[b * 4096 + 1 * 1024 + n];
        const float r2 = reg[b * 4096 + 2 * 1024 + n];
        const float r3 = reg[b * 4096 + 3 * 1024 + n];
        const float w = x2 - x1, h = y2 - y1;
        const float qq1 = x1 + r0 * w;
        const float qq2 = y1 + r1 * h;
        const float qq3 = x2 + r2 * w;
        const float qq4 = y2 + r3 * h;
        const float hh = qq4 - qq2, ww = qq3 - qq1;
        const float l = fmaxf(ww, hh);
        const float rx1 = qq1 + ww * 0.5f - l * 0.5f;
        const float ry1 = qq2 + hh * 0.5f - l * 0.5f;
        const float rx2 = rx1 + l;
        const float ry2 = ry1 + l;
        const float kf = (sst[(y + 1) * 34 + (x + 1)] == ST_KEEP) ? 1.0f : 0.0f;
        float* o = out + (size_t)(b * 1024 + n) * 5;
        o[0] = rx1 * kf;
        o[1] = ry1 * kf;
        o[2] = rx2 * kf;
        o[3] = ry2 * kf;
        o[4] = score * kf;
    }
}

extern "C" void kernel_launch(void* const* d_in, const int* in_sizes, int n_in,
                              void* d_out, int out_size, void* d_ws, size_t ws_size,
                              hipStream_t stream) {
    const float* probs = (const float*)d_in[0];   // 8192 f32
    const float* reg   = (const float*)d_in[1];   // 32768 f32
    float* out = (float*)d_out;                   // 40960 f32
    pnet_kernel<<<8, 256, 0, stream>>>(probs, reg, out);
}

// Round 4
// 17.052 us; speedup vs baseline: 14.6980x; 1.2645x over previous
//
#include <hip/hip_runtime.h>

// MTCNN PNet stage: box gen + greedy NMS + refinement.
// One 64-lane wave per batch (8 blocks x 64 threads). NMS statuses are
// bit-packed: lane y (y<32) owns row y of the 32x32 grid as u32 masks
// (unk, kept). Each fixed-point round = 4 shuffles + bit-ops: no barriers,
// no LDS. The monotone fixed point (KEPT iff all higher-priority conflicting
// neighbors DEAD; DEAD iff any such neighbor KEPT) equals the reference's
// sequential greedy scan exactly (validated: round-3 kernel, absmax 0.0).
//
// Exact-integer geometry (== f64 numpy reference):
//   x1=(20x+10)/3, x2=(20x+120)/3 (int div) -> widths w(x)=38 except
//   x%3==1 -> 37; adjacent-cell interval overlap is always 31.
//   IoU>0.5 <=> 3*inter > areaA+areaB. Cardinal neighbors: 3*31*wy vs
//   (wx+wx')*wy -> 93 > wx+wx' <= 76: ALWAYS conflict. Diagonals:
//   3*961=2883 vs sums {2812,2813,2850,2888}: conflict unless both pair
//   widths are (38,38):
//     dir(+1,+1) non-conflict <=> x%3==2 && y%3==2
//     dir(-1,-1) non-conflict <=> x%3==0 && y%3==0
//     dir(+1,-1) non-conflict <=> x%3==2 && y%3==0
//     dir(-1,+1) non-conflict <=> x%3==0 && y%3==2
//   Conflicts never reach |dx|>=2 or |dy|>=2 (max IoU 0.490).
// Batches cannot suppress each other (offset separation exact) -> per-batch.

constexpr float kThresh = 0.6f;

__global__ __launch_bounds__(64)
void pnet_kernel(const float* __restrict__ probs,   // (8,32,32)
                 const float* __restrict__ reg,     // (8,4,32,32)
                 float* __restrict__ out)           // (8192,5)
{
    const int b = blockIdx.x;
    const int lane = threadIdx.x;      // 0..63

    __shared__ float ssc[1024];

    // ---- stage scores to LDS (coalesced float4) ----
    const float4* p4 = (const float4*)(probs + b * 1024);
    #pragma unroll
    for (int p = 0; p < 4; ++p) {
        const int i = p * 64 + lane;
        ((float4*)ssc)[i] = p4[i];
    }
    __syncthreads();

    // ---- per-row state: lane y<32 owns row y; lanes 32..63 hold zeros ----
    unsigned int m0=0,m1=0,m2=0,m3=0,m4=0,m5=0,m6=0,m7=0;  // hp-conflict dir masks
    unsigned int unk = 0, kept = 0;

    // ---- build masks: 16 ballot passes, 2 rows (64 boxes) per pass ----
    for (int j = 0; j < 16; ++j) {
        const int n = j * 64 + lane;          // box index in batch
        const int x = lane & 31;
        const int y = (j << 1) | (lane >> 5);
        const float sn = ssc[n];
        const int xm3 = x % 3;
        const int ym3 = y % 3;

        unsigned long long bb;

        // hp = neighbor in-bounds && valid && higher priority && IoU>0.5
        // NEGDIR: neighbor's flat index < n (tie-break for equal scores)
#define DO_DIR(DX, DY, NEGDIR, CONF, MV)                                     \
        {                                                                    \
            const int xj = x + (DX), yj = y + (DY);                          \
            const bool inb = ((unsigned)xj < 32u) && ((unsigned)yj < 32u);   \
            const float sj = ssc[(n + (DY) * 32 + (DX)) & 1023];             \
            const bool hp = inb && (sj >= kThresh) &&                        \
                            ((sj > sn) || ((sj == sn) && (NEGDIR))) &&       \
                            (CONF);                                          \
            bb = __ballot(hp);                                               \
            if (lane == 2 * j)     MV = (unsigned int)bb;                    \
            if (lane == 2 * j + 1) MV = (unsigned int)(bb >> 32);            \
        }
        DO_DIR(-1, -1, true,  !(xm3 == 0 && ym3 == 0), m0)
        DO_DIR( 0, -1, true,  true,                    m1)
        DO_DIR(+1, -1, true,  !(xm3 == 2 && ym3 == 0), m2)
        DO_DIR(-1,  0, true,  true,                    m3)
        DO_DIR(+1,  0, false, true,                    m4)
        DO_DIR(-1, +1, false, !(xm3 == 0 && ym3 == 2), m5)
        DO_DIR( 0, +1, false, true,                    m6)
        DO_DIR(+1, +1, false, !(xm3 == 2 && ym3 == 2), m7)
#undef DO_DIR
        bb = __ballot(sn >= kThresh);                    // valid -> UNK init
        if (lane == 2 * j)     unk = (unsigned int)bb;
        if (lane == 2 * j + 1) unk = (unsigned int)(bb >> 32);
    }

    // ---- bit-parallel monotone fixed point (no barriers, no LDS) ----
    // bit x of (S<<1) = neighbor col x-1; (S>>1) = col x+1.
    // lane 0's up-src = lane 63 (zeros), lane 31's down-src = lane 32
    // (zeros) -> border rows see DEAD, as required.
    for (int round = 0; round < 1100; ++round) {
        if (__ballot(unk != 0) == 0ull) break;
        const int up = (lane + 63) & 63;
        const int dn = (lane + 1) & 63;
        const unsigned int unkU = __shfl(unk,  up);
        const unsigned int unkD = __shfl(unk,  dn);
        const unsigned int kU   = __shfl(kept, up);
        const unsigned int kD   = __shfl(kept, dn);
        unsigned int anyK = 0, anyU = 0;
        anyK |= m0 & (kU << 1);    anyU |= m0 & (unkU << 1);
        anyK |= m1 &  kU;          anyU |= m1 &  unkU;
        anyK |= m2 & (kU >> 1);    anyU |= m2 & (unkU >> 1);
        anyK |= m3 & (kept << 1);  anyU |= m3 & (unk  << 1);
        anyK |= m4 & (kept >> 1);  anyU |= m4 & (unk  >> 1);
        anyK |= m5 & (kD << 1);    anyU |= m5 & (unkD << 1);
        anyK |= m6 &  kD;          anyU |= m6 &  unkD;
        anyK |= m7 & (kD >> 1);    anyU |= m7 & (unkD >> 1);
        const unsigned int newkeep = unk & ~anyK & ~anyU;
        const unsigned int newdead = unk & anyK;
        kept |= newkeep;
        unk  &= ~(newdead | newkeep);
    }

    // ---- epilogue: refine, square, gate (identical arithmetic to the
    //      round-2/3 verified version) ----
    const float* regb = reg + b * 4096;
    float* outb = out + (size_t)b * 5120;
    for (int j = 0; j < 16; ++j) {
        const int n = j * 64 + lane;
        const int x = n & 31;
        const int y = n >> 5;                       // 2j or 2j+1, always <32
        const unsigned int krow = __shfl(kept, y);  // per-lane src ok
        const float kf = (float)((krow >> x) & 1u);
        const float score = ssc[n];
        const float x1 = (float)((20 * x + 10) / 3);
        const float y1 = (float)((20 * y + 10) / 3);
        const float x2 = (float)((20 * x + 120) / 3);
        const float y2 = (float)((20 * y + 120) / 3);
        const float r0 = regb[0 * 1024 + n];
        const float r1 = regb[1 * 1024 + n];
        const float r2 = regb[2 * 1024 + n];
        const float r3 = regb[3 * 1024 + n];
        const float w = x2 - x1, h = y2 - y1;
        const float qq1 = x1 + r0 * w;
        const float qq2 = y1 + r1 * h;
        const float qq3 = x2 + r2 * w;
        const float qq4 = y2 + r3 * h;
        const float hh = qq4 - qq2, ww = qq3 - qq1;
        const float l = fmaxf(ww, hh);
        const float rx1 = qq1 + ww * 0.5f - l * 0.5f;
        const float ry1 = qq2 + hh * 0.5f - l * 0.5f;
        const float rx2 = rx1 + l;
        const float ry2 = ry1 + l;
        float* o = outb + n * 5;
        o[0] = rx1 * kf;
        o[1] = ry1 * kf;
        o[2] = rx2 * kf;
        o[3] = ry2 * kf;
        o[4] = score * kf;
    }
}

extern "C" void kernel_launch(void* const* d_in, const int* in_sizes, int n_in,
                              void* d_out, int out_size, void* d_ws, size_t ws_size,
                              hipStream_t stream) {
    const float* probs = (const float*)d_in[0];   // 8192 f32
    const float* reg   = (const float*)d_in[1];   // 32768 f32
    float* out = (float*)d_out;                   // 40960 f32
    pnet_kernel<<<8, 64, 0, stream>>>(probs, reg, out);
}

// Round 5
// 10.562 us; speedup vs baseline: 23.7292x; 1.6145x over previous
//
#include <hip/hip_runtime.h>

// MTCNN PNet stage: box gen + greedy NMS (bit-parallel monotone fixed point,
// exact-match to the reference greedy scan — validated rounds 2-4, absmax 0.0)
// + refinement. 8 blocks (one per batch) x 256 threads (4 waves).
//   wave 0..3 : build hp-conflict masks via ballots (4 passes each) -> LDS
//   wave 0    : bit-packed fixed point (lane y owns row y as u32 masks)
//   all       : epilogue, 4 contiguous boxes/thread, float4 in/out
// reg values are prefetched into registers at kernel entry so HBM latency
// hides under mask build + fixed point (issue-early / wait-late).
//
// Exact-integer geometry (== f64 numpy reference), verified in rounds 2-4:
//   x1=(20x+10)/3, x2=(20x+120)/3 (int div); IoU>0.5 <=> 3*inter > aA+aB.
//   Conflicts confined to 3x3 neighborhood; cardinals always conflict;
//   diagonals conflict unless both pair-widths are 38 (mod-3 phase rule).
//   Batches cannot suppress each other (exact offset separation).

constexpr float kThresh = 0.6f;

__global__ __launch_bounds__(256)
void pnet_kernel(const float* __restrict__ probs,   // (8,32,32)
                 const float* __restrict__ reg,     // (8,4,32,32)
                 float* __restrict__ out)           // (8192,5)
{
    const int b    = blockIdx.x;
    const int t    = threadIdx.x;
    const int lane = t & 63;
    const int wave = t >> 6;

    __shared__ float        ssc[1024];
    __shared__ unsigned int smk[9][32];     // [dir0..7, unk=8][row]
    __shared__ unsigned int skeepRow[32];   // final kept bitmap per row

    // ---- prefetch: issue ALL global loads up front, wait at use ----
    const float4* r4 = (const float4*)(reg + b * 4096);
    const float4 rv0 = r4[0 * 256 + t];     // reg[b,0, 4t..4t+3]
    const float4 rv1 = r4[1 * 256 + t];
    const float4 rv2 = r4[2 * 256 + t];
    const float4 rv3 = r4[3 * 256 + t];
    const float4 sc4 = ((const float4*)(probs + b * 1024))[t];  // own scores

    ((float4*)ssc)[t] = sc4;
    __syncthreads();

    // ---- mask build: wave w does passes j = 4w..4w+3 (ballots wave-local,
    //      pass j covers boxes j*64..j*64+63 = rows 2j,2j+1) ----
    #pragma unroll
    for (int jj = 0; jj < 4; ++jj) {
        const int j = (wave << 2) | jj;
        const int n = (j << 6) | lane;
        const int x = lane & 31;
        const int y = (j << 1) | (lane >> 5);
        const float sn = ssc[n];
        const int xm3 = x % 3, ym3 = y % 3;
        unsigned long long bb;

        // hp = in-bounds && valid && higher-priority (score desc, idx asc)
        //      && IoU>0.5 (phase rule)
#define DO_DIR(DX, DY, NEGDIR, CONF, IDX)                                   \
        {                                                                   \
            const int xj = x + (DX), yj = y + (DY);                         \
            const bool inb = ((unsigned)xj < 32u) && ((unsigned)yj < 32u);  \
            const float sj = ssc[(n + (DY) * 32 + (DX)) & 1023];            \
            const bool hp = inb && (sj >= kThresh) &&                       \
                            ((sj > sn) || ((sj == sn) && (NEGDIR))) &&      \
                            (CONF);                                         \
            bb = __ballot(hp);                                              \
            if (lane < 2)                                                   \
                smk[IDX][(j << 1) | lane] =                                 \
                    lane ? (unsigned int)(bb >> 32) : (unsigned int)bb;     \
        }
        DO_DIR(-1, -1, true,  !(xm3 == 0 && ym3 == 0), 0)
        DO_DIR( 0, -1, true,  true,                    1)
        DO_DIR(+1, -1, true,  !(xm3 == 2 && ym3 == 0), 2)
        DO_DIR(-1,  0, true,  true,                    3)
        DO_DIR(+1,  0, false, true,                    4)
        DO_DIR(-1, +1, false, !(xm3 == 0 && ym3 == 2), 5)
        DO_DIR( 0, +1, false, true,                    6)
        DO_DIR(+1, +1, false, !(xm3 == 2 && ym3 == 2), 7)
#undef DO_DIR
        bb = __ballot(sn >= kThresh);   // valid boxes start UNKNOWN
        if (lane < 2)
            smk[8][(j << 1) | lane] =
                lane ? (unsigned int)(bb >> 32) : (unsigned int)bb;
    }
    __syncthreads();

    // ---- fixed point on wave 0: no barriers, no LDS in the loop ----
    if (wave == 0) {
        unsigned int m0=0,m1=0,m2=0,m3=0,m4=0,m5=0,m6=0,m7=0;
        unsigned int unk = 0, kept = 0;
        if (lane < 32) {
            m0 = smk[0][lane]; m1 = smk[1][lane];
            m2 = smk[2][lane]; m3 = smk[3][lane];
            m4 = smk[4][lane]; m5 = smk[5][lane];
            m6 = smk[6][lane]; m7 = smk[7][lane];
            unk = smk[8][lane];
        }
        const int up = (lane + 63) & 63;   // lane 0 -> 63 (zeros = border)
        const int dn = (lane + 1)  & 63;   // lane 31 -> 32 (zeros = border)

#define STEP                                                                \
        {                                                                   \
            const unsigned int unkU = __shfl(unk,  up);                     \
            const unsigned int unkD = __shfl(unk,  dn);                     \
            const unsigned int kU   = __shfl(kept, up);                     \
            const unsigned int kD   = __shfl(kept, dn);                     \
            unsigned int anyK, anyU;                                        \
            anyK  = m0 & (kU << 1);    anyU  = m0 & (unkU << 1);            \
            anyK |= m1 &  kU;          anyU |= m1 &  unkU;                  \
            anyK |= m2 & (kU >> 1);    anyU |= m2 & (unkU >> 1);            \
            anyK |= m3 & (kept << 1);  anyU |= m3 & (unk  << 1);            \
            anyK |= m4 & (kept >> 1);  anyU |= m4 & (unk  >> 1);            \
            anyK |= m5 & (kD << 1);    anyU |= m5 & (unkD << 1);            \
            anyK |= m6 &  kD;          anyU |= m6 &  unkD;                  \
            anyK |= m7 & (kD >> 1);    anyU |= m7 & (unkD >> 1);            \
            const unsigned int nk = unk & ~anyK;                            \
            kept |= nk & ~anyU;                                             \
            unk   = nk &  anyU;                                             \
        }
        for (int r = 0; r < 600; ++r) {     // converges in ~tens of steps;
            STEP                            // extra steps are no-ops
            STEP
            if (__ballot(unk != 0) == 0ull) break;
        }
#undef STEP
        if (lane < 32) skeepRow[lane] = kept;
    }
    __syncthreads();

    // ---- epilogue: thread t owns boxes 4t..4t+3 (row y, cols x0..x0+3);
    //      arithmetic identical to the round-2..4 verified version ----
    const int y  = t >> 3;
    const int x0 = (t & 7) << 2;
    const unsigned int krow = skeepRow[y];
    const float fy1 = (float)((20 * y + 10) / 3);
    const float fy2 = (float)((20 * y + 120) / 3);
    const float h   = fy2 - fy1;

    float4 o4[5];
    float* o = (float*)o4;
    #pragma unroll
    for (int k = 0; k < 4; ++k) {
        const int x = x0 + k;
        const float score = (k == 0) ? sc4.x : (k == 1) ? sc4.y
                          : (k == 2) ? sc4.z : sc4.w;
        const float r0 = (k == 0) ? rv0.x : (k == 1) ? rv0.y
                       : (k == 2) ? rv0.z : rv0.w;
        const float r1 = (k == 0) ? rv1.x : (k == 1) ? rv1.y
                       : (k == 2) ? rv1.z : rv1.w;
        const float r2 = (k == 0) ? rv2.x : (k == 1) ? rv2.y
                       : (k == 2) ? rv2.z : rv2.w;
        const float r3 = (k == 0) ? rv3.x : (k == 1) ? rv3.y
                       : (k == 2) ? rv3.z : rv3.w;
        const float x1 = (float)((20 * x + 10) / 3);
        const float x2 = (float)((20 * x + 120) / 3);
        const float w  = x2 - x1;
        const float qq1 = x1  + r0 * w;
        const float qq2 = fy1 + r1 * h;
        const float qq3 = x2  + r2 * w;
        const float qq4 = fy2 + r3 * h;
        const float hh = qq4 - qq2, ww = qq3 - qq1;
        const float l = fmaxf(ww, hh);
        const float rx1 = qq1 + ww * 0.5f - l * 0.5f;
        const float ry1 = qq2 + hh * 0.5f - l * 0.5f;
        const float kf = (float)((krow >> x) & 1u);
        o[5 * k + 0] = rx1 * kf;
        o[5 * k + 1] = ry1 * kf;
        o[5 * k + 2] = (rx1 + l) * kf;
        o[5 * k + 3] = (ry1 + l) * kf;
        o[5 * k + 4] = score * kf;
    }
    float4* ob = (float4*)(out + (size_t)b * 5120 + t * 20);
    #pragma unroll
    for (int q = 0; q < 5; ++q) ob[q] = o4[q];
}

extern "C" void kernel_launch(void* const* d_in, const int* in_sizes, int n_in,
                              void* d_out, int out_size, void* d_ws, size_t ws_size,
                              hipStream_t stream) {
    const float* probs = (const float*)d_in[0];   // 8192 f32
    const float* reg   = (const float*)d_in[1];   // 32768 f32
    float* out = (float*)d_out;                   // 40960 f32
    pnet_kernel<<<8, 256, 0, stream>>>(probs, reg, out);
}